// Round 7
// baseline (145.931 us; speedup 1.0000x reference)
//
#include <hip/hip_runtime.h>
#include <math.h>

#define D_BINS 59
#define CO     64
#define CI     256
#define NB     4
#define NC     6
#define H_IMG  16
#define W_IMG  44
#define HW     704            // H_IMG * W_IMG
#define NPIX   (NB*NC*HW)     // 16896
#define XD     128
#define YD     128
#define ZD     7
#define NOUT   123            // D_BINS + CO
#define NS     (NC*ZD)        // 42 samples per BEV cell
#define APAD   260            // A_lds row stride (px): 260%32=4 -> <=2-way write conflicts

typedef float v2f __attribute__((ext_vector_type(2)));

// ---------------------------------------------------------------------------
// Double-precision rigid-transform inverse (matches np.linalg.inv to ~1e-15,
// avoiding depth-bin boundary flips downstream).
// ---------------------------------------------------------------------------
__device__ void inv_rigid(const float* __restrict__ M, float* __restrict__ o) {
    double a = M[0], b = M[1], c = M[2], t0 = M[3];
    double d = M[4], e = M[5], f = M[6], t1 = M[7];
    double g = M[8], h = M[9], ii = M[10], t2 = M[11];
    double A00 = e*ii - f*h, A01 = c*h - b*ii, A02 = b*f - c*e;
    double A10 = f*g - d*ii, A11 = a*ii - c*g, A12 = c*d - a*f;
    double A20 = d*h - e*g,  A21 = b*g - a*h,  A22 = a*e - b*d;
    double det = a*A00 + b*A10 + c*A20;
    double inv = 1.0 / det;
    double r00 = A00*inv, r01 = A01*inv, r02 = A02*inv;
    double r10 = A10*inv, r11 = A11*inv, r12 = A12*inv;
    double r20 = A20*inv, r21 = A21*inv, r22 = A22*inv;
    o[0] = (float)r00; o[1] = (float)r01; o[2]  = (float)r02;
    o[3] = (float)(-(r00*t0 + r01*t1 + r02*t2));
    o[4] = (float)r10; o[5] = (float)r11; o[6]  = (float)r12;
    o[7] = (float)(-(r10*t0 + r11*t1 + r12*t2));
    o[8] = (float)r20; o[9] = (float)r21; o[10] = (float)r22;
    o[11] = (float)(-(r20*t0 + r21*t1 + r22*t2));
}

// ---------------------------------------------------------------------------
// Kernel 1: depth/feat head. 2112 independent single-wave blocks, 8 px each
// (2112*8 == NPIX; 8 | 704 so a tile never crosses (b,n)). Lane l owns output
// rows o=l and o=l+64 with W held in VGPRs (per kc: 2x64 floats, loaded from
// the L2-resident 126 KB wd). A tile staged once in LDS (pad APAD) and read
// as uniform-address ds_read_b128 broadcasts. Inner: 16 b128 + 64 pk_fma per
// px per kc. Softmax via cross-lane butterfly (bins live one-per-lane).
// No inter-wave barriers; 8.25 waves/CU for latency hiding.
// ---------------------------------------------------------------------------
__global__ __launch_bounds__(64, 2) void k_head(
    const float* __restrict__ img, const float* __restrict__ wd,
    const float* __restrict__ bd, float* __restrict__ depth_out,
    float* __restrict__ feat_ws) {
    __shared__ float A[8 * APAD];

    const int l  = threadIdx.x;          // 0..63
    const int p0 = blockIdx.x * 8;
    const int bn = p0 / HW;              // uniform (8 divides 704)
    const int hw0 = p0 - bn * HW;

    // ---- stage A: 256 k x 8 px into LDS (lane: px=l&7, k-offset=l>>3) ----
    {
        const int px = l & 7, ko = l >> 3;
        const float* gsrc = img + (size_t)bn * CI * HW + hw0 + px;
        float* ldst = A + px * APAD + ko;
#pragma unroll 8
        for (int it = 0; it < 32; ++it)
            ldst[it * 8] = gsrc[(size_t)(it * 8 + ko) * HW];
    }
    __syncthreads();

    const int r1 = (l + 64 < NOUT) ? (l + 64) : (NOUT - 1);  // clamp; lanes 59..63 unused
    const float* w0p = wd + (size_t)l * CI;
    const float* w1p = wd + (size_t)r1 * CI;

    float accA[8], accB[8];
#pragma unroll
    for (int p = 0; p < 8; ++p) { accA[p] = 0.f; accB[p] = 0.f; }

    for (int kc = 0; kc < 4; ++kc) {
        // W chunk for this lane's two rows -> registers (128 VGPRs)
        v2f w0[32], w1[32];
#pragma unroll
        for (int q = 0; q < 16; ++q) {
            float4 t0 = *(const float4*)(w0p + kc * 64 + q * 4);
            w0[2 * q]     = (v2f){t0.x, t0.y};
            w0[2 * q + 1] = (v2f){t0.z, t0.w};
            float4 t1 = *(const float4*)(w1p + kc * 64 + q * 4);
            w1[2 * q]     = (v2f){t1.x, t1.y};
            w1[2 * q + 1] = (v2f){t1.z, t1.w};
        }
#pragma unroll
        for (int px = 0; px < 8; ++px) {
            const float* ap = A + px * APAD + kc * 64;   // uniform -> broadcast
            v2f s0 = (v2f)(0.f), s1 = (v2f)(0.f);
#pragma unroll
            for (int q = 0; q < 16; ++q) {
                float4 a4 = *(const float4*)(ap + q * 4);
                v2f a01 = (v2f){a4.x, a4.y};
                v2f a23 = (v2f){a4.z, a4.w};
                s0 = __builtin_elementwise_fma(a01, w0[2 * q], s0);
                s0 = __builtin_elementwise_fma(a23, w0[2 * q + 1], s0);
                s1 = __builtin_elementwise_fma(a01, w1[2 * q], s1);
                s1 = __builtin_elementwise_fma(a23, w1[2 * q + 1], s1);
            }
            accA[px] += s0.x + s0.y;
            accB[px] += s1.x + s1.y;
        }
    }

    // ---- epilogue: bias, cross-lane softmax over lanes 0..58, stores ----
    const float b0 = bd[l];                                   // l <= 63 < 123
    const float b1 = (l + 64 < NOUT) ? bd[l + 64] : 0.f;
#pragma unroll
    for (int px = 0; px < 8; ++px) {
        const float x0 = accA[px] + b0;   // o = l
        const float x1 = accB[px] + b1;   // o = l + 64 (valid if < 123)
        // max over depth bins (lanes 0..58)
        float mx = (l < D_BINS) ? x0 : -INFINITY;
#pragma unroll
        for (int m = 1; m < 64; m <<= 1) mx = fmaxf(mx, __shfl_xor(mx, m));
        const float e = (l < D_BINS) ? __expf(x0 - mx) : 0.f;
        float s = e;
#pragma unroll
        for (int m = 1; m < 64; m <<= 1) s += __shfl_xor(s, m);
        const size_t p = p0 + px;
        if (l < D_BINS) depth_out[p * D_BINS + l] = e / s;
        float* fb = feat_ws + p * CO;
        if (l >= D_BINS) fb[l - D_BINS] = x0;        // feat c = 0..4
        if (l + 64 < NOUT) fb[l + 5] = x1;           // feat c = 5..63
    }
}

// ---------------------------------------------------------------------------
// Kernel 2: project voxels, gather depth weight + feat, splat to BEV.
// 1024 blocks (4/CU, 16 waves/CU). ONE projection phase computes all 42
// (n,z) samples' {hw, weight} per cell into LDS (each wave cq handles
// s = cq, cq+4, ... -> wave-uniform loop), ONE barrier, then an accumulate
// phase with 42 independent gather iterations (deep MLP; was 12 barriers).
// Float expressions and n-outer/z-ascending FMA order preserved verbatim.
// ---------------------------------------------------------------------------
__global__ __launch_bounds__(256) void k_splat(
    const float* __restrict__ c2e, const float* __restrict__ Kmat,
    const float* __restrict__ depth_g, const float* __restrict__ feat_ws,
    float* __restrict__ bev) {
    __shared__ int   hw_s[NS][64];
    __shared__ float wgt_s[NS][64];
    __shared__ float E_s[NC][12];

    const int tx = threadIdx.x;          // 0..63 -> x
    const int cq = threadIdx.y;          // 0..3  -> channel quarter / sample slice
    const int x = blockIdx.x * 64 + tx;
    const int y = blockIdx.y;
    const int b = blockIdx.z;

    if (cq == 0 && tx < NC)
        inv_rigid(c2e + (size_t)(b * NC + tx) * 16, &E_s[tx][0]);
    __syncthreads();

    const float wx = (float)x * 0.8f + (-51.2f);
    const float wy = (float)y * 0.8f + (-51.2f);

    // ---- projection phase: wave cq owns samples s = cq, cq+4, ... ----
    for (int s = cq; s < NS; s += 4) {
        const int n = s / ZD;
        const int z = s - n * ZD;
        const int bn = b * NC + n;
        const float* E = &E_s[n][0];
        const float* Km = Kmat + bn * 9;
        const float bx0 = E[0] * wx + E[1] * wy + E[3];
        const float bx1 = E[4] * wx + E[5] * wy + E[7];
        const float bx2 = E[8] * wx + E[9] * wy + E[11];
        const float wz = -2.5f + (float)z;
        const float cx = bx0 + E[2]  * wz;
        const float cy = bx1 + E[6]  * wz;
        const float cz = bx2 + E[10] * wz;
        const float zs = fmaxf(cz, 0.1f);
        const float rz = 1.0f / zs;                 // IEEE divide
        const float xn = cx * rz;
        const float yn = cy * rz;
        const float fu = (Km[0] * xn + Km[1] * yn + Km[2]) * 0.0625f;
        const float fv = (Km[3] * xn + Km[4] * yn + Km[5]) * 0.0625f;
        const int bin = (int)(cz - 1.0f);           // trunc, matches astype(int32)
        const bool valid = (fu >= 0.f) & (fu < (float)W_IMG) &
                           (fv >= 0.f) & (fv < (float)H_IMG) &
                           (cz > 0.5f) & (bin >= 0) & (bin < D_BINS);
        int hw = -1;
        float wgt = 0.f;
        if (valid) {
            int u = (int)fu;                        // valid => in range
            int v = (int)fv;
            hw = v * W_IMG + u;
            wgt = depth_g[((size_t)bn * HW + hw) * D_BINS + bin];
        }
        hw_s[s][tx] = hw;
        wgt_s[s][tx] = wgt;
    }
    __syncthreads();

    // ---- accumulate phase: n-outer, z-ascending (reference FMA order) ----
    float acc[16];
#pragma unroll
    for (int m = 0; m < 16; ++m) acc[m] = 0.f;

    for (int n = 0; n < NC; ++n) {
        const int bn = b * NC + n;
        const float* fbase = feat_ws + (size_t)bn * HW * CO + cq * 16;
#pragma unroll
        for (int z = 0; z < ZD; ++z) {
            const int s = n * ZD + z;
            const int hw = hw_s[s][tx];       // same addr across cq: broadcast
            if (hw >= 0) {
                const float wgt = wgt_s[s][tx];
                const float4* fp = (const float4*)(fbase + (size_t)hw * CO);
                float4 f0 = fp[0], f1 = fp[1], f2 = fp[2], f3 = fp[3];
                acc[0]  = fmaf(wgt, f0.x, acc[0]);
                acc[1]  = fmaf(wgt, f0.y, acc[1]);
                acc[2]  = fmaf(wgt, f0.z, acc[2]);
                acc[3]  = fmaf(wgt, f0.w, acc[3]);
                acc[4]  = fmaf(wgt, f1.x, acc[4]);
                acc[5]  = fmaf(wgt, f1.y, acc[5]);
                acc[6]  = fmaf(wgt, f1.z, acc[6]);
                acc[7]  = fmaf(wgt, f1.w, acc[7]);
                acc[8]  = fmaf(wgt, f2.x, acc[8]);
                acc[9]  = fmaf(wgt, f2.y, acc[9]);
                acc[10] = fmaf(wgt, f2.z, acc[10]);
                acc[11] = fmaf(wgt, f2.w, acc[11]);
                acc[12] = fmaf(wgt, f3.x, acc[12]);
                acc[13] = fmaf(wgt, f3.y, acc[13]);
                acc[14] = fmaf(wgt, f3.z, acc[14]);
                acc[15] = fmaf(wgt, f3.w, acc[15]);
            }
        }
    }
    // out[b][c][y][x], c = cq*16 + m; 64 lanes = consecutive x -> coalesced
    float* ob = bev + (((size_t)b * CO + cq * 16) * YD + y) * XD + x;
#pragma unroll
    for (int m = 0; m < 16; ++m) ob[(size_t)m * YD * XD] = acc[m];
}

extern "C" void kernel_launch(void* const* d_in, const int* in_sizes, int n_in,
                              void* d_out, int out_size, void* d_ws, size_t ws_size,
                              hipStream_t stream) {
    const float* img  = (const float*)d_in[0];  // (B,N,256,16,44)
    const float* c2e  = (const float*)d_in[1];  // (B,N,4,4)
    const float* Kmat = (const float*)d_in[2];  // (B,N,3,3)
    const float* wd   = (const float*)d_in[3];  // (123,256)
    const float* bd   = (const float*)d_in[4];  // (123,)
    float* bev = (float*)d_out;                         // (B,64,128,128)
    float* depth_out = bev + (size_t)NB * CO * YD * XD; // (B,N,16,44,59)
    float* feat_ws = (float*)d_ws;                      // NPIX*64 floats

    k_head<<<NPIX / 8, 64, 0, stream>>>(img, wd, bd, depth_out, feat_ws);
    k_splat<<<dim3(2, YD, NB), dim3(64, 4, 1), 0, stream>>>(c2e, Kmat, depth_out,
                                                            feat_ws, bev);
}

// Round 8
// 132.329 us; speedup vs baseline: 1.1028x; 1.1028x over previous
//
#include <hip/hip_runtime.h>
#include <math.h>

#define D_BINS 59
#define CO     64
#define CI     256
#define NB     4
#define NC     6
#define H_IMG  16
#define W_IMG  44
#define HW     704            // H_IMG * W_IMG
#define NPIX   (NB*NC*HW)     // 16896
#define XD     128
#define YD     128
#define ZD     7
#define NOUT   123            // D_BINS + CO

typedef float v2f __attribute__((ext_vector_type(2)));

// ---------------------------------------------------------------------------
// Double-precision rigid-transform inverse (matches np.linalg.inv to ~1e-15,
// avoiding depth-bin boundary flips downstream).
// ---------------------------------------------------------------------------
__device__ void inv_rigid(const float* __restrict__ M, float* __restrict__ o) {
    double a = M[0], b = M[1], c = M[2], t0 = M[3];
    double d = M[4], e = M[5], f = M[6], t1 = M[7];
    double g = M[8], h = M[9], ii = M[10], t2 = M[11];
    double A00 = e*ii - f*h, A01 = c*h - b*ii, A02 = b*f - c*e;
    double A10 = f*g - d*ii, A11 = a*ii - c*g, A12 = c*d - a*f;
    double A20 = d*h - e*g,  A21 = b*g - a*h,  A22 = a*e - b*d;
    double det = a*A00 + b*A10 + c*A20;
    double inv = 1.0 / det;
    double r00 = A00*inv, r01 = A01*inv, r02 = A02*inv;
    double r10 = A10*inv, r11 = A11*inv, r12 = A12*inv;
    double r20 = A20*inv, r21 = A21*inv, r22 = A22*inv;
    o[0] = (float)r00; o[1] = (float)r01; o[2]  = (float)r02;
    o[3] = (float)(-(r00*t0 + r01*t1 + r02*t2));
    o[4] = (float)r10; o[5] = (float)r11; o[6]  = (float)r12;
    o[7] = (float)(-(r10*t0 + r11*t1 + r12*t2));
    o[8] = (float)r20; o[9] = (float)r21; o[10] = (float)r22;
    o[11] = (float)(-(r20*t0 + r21*t1 + r22*t2));
}

// ---------------------------------------------------------------------------
// Kernel 1: prep. W (123x256) -> wt2, k-pair-interleaved + transposed:
//   wt2[(k/2)*256 + o*2 + (k&1)],  o zero-padded to 128.
// Each wave's 8-output strip is then 16 CONTIGUOUS floats per k-pair ->
// a single s_load_dwordx16 through the scalar cache in k_head.
// ---------------------------------------------------------------------------
__global__ __launch_bounds__(256) void k_pre(
    const float* __restrict__ wd, float* __restrict__ wt2) {
    const int o = blockIdx.x;   // 0..127
    const int k = threadIdx.x;  // 0..255
    float v = (o < NOUT) ? wd[(size_t)o * CI + k] : 0.f;
    wt2[(size_t)(k >> 1) * 256 + o * 2 + (k & 1)] = v;
}

// ---------------------------------------------------------------------------
// Kernel 2: depth/feat head. 264 blocks x 1024 threads (16 waves), tile
// 64 px x 128 o. Wave wv owns the 8-output strip o0 = 8*wv (wave-uniform ->
// one s_load_dwordx16 of W per k-pair); lane = px reads A as conflict-free
// ds_read_b64 from the k-pair-interleaved LDS tile; 8 v_pk_fma_f32 per k2.
// __launch_bounds__(1024,8) caps VGPR at 64 -> 8 waves/SIMD latency hiding
// (R5's identical dataflow starved at 2.5 waves/SIMD). Per-output k-order
// identical to R5 -> same numerics. Epilogue: X[64][132] in LDS, cross-
// checked softmax per px, coalesced depth/feat stores.
// ---------------------------------------------------------------------------
__global__ __launch_bounds__(1024, 8) void k_head(
    const float* __restrict__ img, const float* __restrict__ wt2,
    const float* __restrict__ bd, float* __restrict__ depth_out,
    float* __restrict__ feat_ws) {
    __shared__ float smem[64 * 132 + 64];  // A: first 32*130 floats; X after GEMM
    float* S = smem + 64 * 132;

    const int tid = threadIdx.x;         // 0..1023
    const int wv  = tid >> 6;            // 0..15
    const int ln  = tid & 63;            // px
    const int p0  = blockIdx.x * 64;     // 64 | 704 -> tile never crosses (b,n)
    const int bn  = p0 / HW;
    const int hw0 = p0 - bn * HW;
    const int o0  = __builtin_amdgcn_readfirstlane(wv << 3);  // wave-uniform

    const float* imgb = img + (size_t)bn * CI * HW + hw0;

    v2f acc[8];                           // {even-k, odd-k} partial sums
#pragma unroll
    for (int j = 0; j < 8; ++j) acc[j] = (v2f)(0.f);

    for (int kc = 0; kc < 4; ++kc) {
        // stage A chunk: 64 k x 64 px, k-pair interleaved, row stride 130.
        // Per instr: kl = wv + it*16 (wave-uniform), px = ln -> coalesced
        // global reads, 2-way (free) LDS write conflicts.
#pragma unroll
        for (int it = 0; it < 4; ++it) {
            int i = tid + it * 1024;
            int kl = i >> 6, px = i & 63;
            smem[(kl >> 1) * 130 + px * 2 + (kl & 1)] =
                imgb[(size_t)(kc * 64 + kl) * HW + px];
        }
        __syncthreads();
#pragma unroll 4
        for (int k2 = 0; k2 < 32; ++k2) {
            v2f a = *(const v2f*)(smem + k2 * 130 + ln * 2);  // conflict-free b64
            const v2f* w =
                (const v2f*)(wt2 + (size_t)(kc * 32 + k2) * 256) + o0;  // s_load x16
#pragma unroll
            for (int j = 0; j < 8; ++j)
                acc[j] = __builtin_elementwise_fma(a, w[j], acc[j]);
        }
        __syncthreads();
    }

    // epilogue into X[64][132]: logits at col o (<59), feat at col o+5 (64..127)
    float* X = smem;
#pragma unroll
    for (int j = 0; j < 8; ++j) {
        int o = o0 + j;
        if (o < NOUT) {
            int col = (o < D_BINS) ? o : o + 5;
            X[ln * 132 + col] = (acc[j].x + acc[j].y) + bd[o];
        }
    }
    __syncthreads();

    // feat: X[p][64..127] -> feat_ws[(p0+p)*64 ...]; 1024 float4s, 1/thread
    {
        int p = tid >> 4, m = tid & 15;
        float4 v = *(const float4*)(X + p * 132 + 64 + m * 4);
        *(float4*)(feat_ws + (size_t)(p0 + p) * CO + m * 4) = v;
    }

    // softmax over cols 0..58, one thread per pixel
    if (tid < 64) {
        float* row = X + tid * 132;
        float m = row[0];
        for (int o = 1; o < D_BINS; ++o) m = fmaxf(m, row[o]);
        float s = 0.f;
        for (int o = 0; o < D_BINS; ++o) {
            float e = __expf(row[o] - m);
            row[o] = e;
            s += e;
        }
        S[tid] = 1.f / s;
    }
    __syncthreads();

    // depth: block region contiguous [p0*59, (p0+64)*59) -> coalesced
    for (int g = tid; g < 64 * D_BINS; g += 1024) {
        int p = g / D_BINS;
        int o = g - p * D_BINS;
        depth_out[(size_t)p0 * D_BINS + g] = X[p * 132 + o] * S[p];
    }
}

// ---------------------------------------------------------------------------
// Kernel 3: project voxels, gather depth weight + feat, splat to BEV.
// Verbatim R6 version (z-phased; R7's single-phase variant regressed ~9 us).
// 1024 blocks (4/CU). cam2ego inverses computed in the block prologue
// (lanes 0..5 of wave 0, double precision) into LDS. Per camera n: a
// projection phase computes each (x,z) sample's {hw, weight} once into LDS;
// accumulate phase broadcasts to the 4 channel-quarter threads.
// ---------------------------------------------------------------------------
__global__ __launch_bounds__(256) void k_splat(
    const float* __restrict__ c2e, const float* __restrict__ Kmat,
    const float* __restrict__ depth_g, const float* __restrict__ feat_ws,
    float* __restrict__ bev) {
    __shared__ int   hw_s[ZD][64];
    __shared__ float wgt_s[ZD][64];
    __shared__ float E_s[NC][12];

    const int tx = threadIdx.x;          // 0..63 -> x
    const int cq = threadIdx.y;          // 0..3  -> channel quarter / z-slice
    const int x = blockIdx.x * 64 + tx;
    const int y = blockIdx.y;
    const int b = blockIdx.z;

    if (cq == 0 && tx < NC)
        inv_rigid(c2e + (size_t)(b * NC + tx) * 16, &E_s[tx][0]);
    __syncthreads();

    const float wx = (float)x * 0.8f + (-51.2f);
    const float wy = (float)y * 0.8f + (-51.2f);

    float acc[16];
#pragma unroll
    for (int m = 0; m < 16; ++m) acc[m] = 0.f;

    for (int n = 0; n < NC; ++n) {
        const int bn = b * NC + n;
        const float* E = &E_s[n][0];
        const float* Km = Kmat + bn * 9;
        const float k00 = Km[0], k01 = Km[1], k02 = Km[2];
        const float k10 = Km[3], k11 = Km[4], k12 = Km[5];
        const float e02 = E[2], e12 = E[6], e22 = E[10];
        const float bx0 = E[0] * wx + E[1] * wy + E[3];
        const float bx1 = E[4] * wx + E[5] * wy + E[7];
        const float bx2 = E[8] * wx + E[9] * wy + E[11];

        // ---- projection phase: thread (tx,cq) owns z = cq and cq+4 ----
#pragma unroll
        for (int zz = 0; zz < 2; ++zz) {
            const int z = cq + zz * 4;
            if (z < ZD) {
                const float wz = -2.5f + (float)z;
                const float cx = bx0 + e02 * wz;
                const float cy = bx1 + e12 * wz;
                const float cz = bx2 + e22 * wz;
                const float zs = fmaxf(cz, 0.1f);
                const float rz = 1.0f / zs;         // IEEE divide
                const float xn = cx * rz;
                const float yn = cy * rz;
                const float fu = (k00 * xn + k01 * yn + k02) * 0.0625f;
                const float fv = (k10 * xn + k11 * yn + k12) * 0.0625f;
                const int bin = (int)(cz - 1.0f);   // trunc, matches astype(int32)
                const bool valid = (fu >= 0.f) & (fu < (float)W_IMG) &
                                   (fv >= 0.f) & (fv < (float)H_IMG) &
                                   (cz > 0.5f) & (bin >= 0) & (bin < D_BINS);
                int hw = -1;
                float wgt = 0.f;
                if (valid) {
                    int u = (int)fu;                // valid => in range
                    int v = (int)fv;
                    hw = v * W_IMG + u;
                    wgt = depth_g[((size_t)bn * HW + hw) * D_BINS + bin];
                }
                hw_s[z][tx] = hw;
                wgt_s[z][tx] = wgt;
            }
        }
        __syncthreads();

        // ---- accumulate phase: z ascending ----
#pragma unroll
        for (int z = 0; z < ZD; ++z) {
            const int hw = hw_s[z][tx];       // same addr across cq: broadcast
            if (hw >= 0) {
                const float wgt = wgt_s[z][tx];
                const float4* fp =
                    (const float4*)(feat_ws + ((size_t)bn * HW + hw) * CO + cq * 16);
                float4 f0 = fp[0], f1 = fp[1], f2 = fp[2], f3 = fp[3];
                acc[0]  = fmaf(wgt, f0.x, acc[0]);
                acc[1]  = fmaf(wgt, f0.y, acc[1]);
                acc[2]  = fmaf(wgt, f0.z, acc[2]);
                acc[3]  = fmaf(wgt, f0.w, acc[3]);
                acc[4]  = fmaf(wgt, f1.x, acc[4]);
                acc[5]  = fmaf(wgt, f1.y, acc[5]);
                acc[6]  = fmaf(wgt, f1.z, acc[6]);
                acc[7]  = fmaf(wgt, f1.w, acc[7]);
                acc[8]  = fmaf(wgt, f2.x, acc[8]);
                acc[9]  = fmaf(wgt, f2.y, acc[9]);
                acc[10] = fmaf(wgt, f2.z, acc[10]);
                acc[11] = fmaf(wgt, f2.w, acc[11]);
                acc[12] = fmaf(wgt, f3.x, acc[12]);
                acc[13] = fmaf(wgt, f3.y, acc[13]);
                acc[14] = fmaf(wgt, f3.z, acc[14]);
                acc[15] = fmaf(wgt, f3.w, acc[15]);
            }
        }
        __syncthreads();   // LDS reused next n
    }
    // out[b][c][y][x], c = cq*16 + m; 64 lanes = consecutive x -> coalesced
    float* ob = bev + (((size_t)b * CO + cq * 16) * YD + y) * XD + x;
#pragma unroll
    for (int m = 0; m < 16; ++m) ob[(size_t)m * YD * XD] = acc[m];
}

extern "C" void kernel_launch(void* const* d_in, const int* in_sizes, int n_in,
                              void* d_out, int out_size, void* d_ws, size_t ws_size,
                              hipStream_t stream) {
    const float* img  = (const float*)d_in[0];  // (B,N,256,16,44)
    const float* c2e  = (const float*)d_in[1];  // (B,N,4,4)
    const float* Kmat = (const float*)d_in[2];  // (B,N,3,3)
    const float* wd   = (const float*)d_in[3];  // (123,256)
    const float* bd   = (const float*)d_in[4];  // (123,)
    float* bev = (float*)d_out;                         // (B,64,128,128)
    float* depth_out = bev + (size_t)NB * CO * YD * XD; // (B,N,16,44,59)
    float* feat_ws = (float*)d_ws;                      // NPIX*64 floats
    float* wt2 = feat_ws + (size_t)NPIX * CO;           // 128*256 floats

    k_pre<<<128, 256, 0, stream>>>(wd, wt2);
    k_head<<<NPIX / 64, 1024, 0, stream>>>(img, wt2, bd, depth_out, feat_ws);
    k_splat<<<dim3(2, YD, NB), dim3(64, 4, 1), 0, stream>>>(c2e, Kmat, depth_out,
                                                            feat_ws, bev);
}

// Round 9
// 127.320 us; speedup vs baseline: 1.1462x; 1.0393x over previous
//
#include <hip/hip_runtime.h>
#include <math.h>

#define D_BINS 59
#define CO     64
#define CI     256
#define NB     4
#define NC     6
#define H_IMG  16
#define W_IMG  44
#define HW     704            // H_IMG * W_IMG
#define NPIX   (NB*NC*HW)     // 16896
#define XD     128
#define YD     128
#define ZD     7
#define NOUT   123            // D_BINS + CO

typedef float v2f __attribute__((ext_vector_type(2)));

// ---------------------------------------------------------------------------
// Double-precision rigid-transform inverse (matches np.linalg.inv to ~1e-15,
// avoiding depth-bin boundary flips downstream).
// ---------------------------------------------------------------------------
__device__ void inv_rigid(const float* __restrict__ M, float* __restrict__ o) {
    double a = M[0], b = M[1], c = M[2], t0 = M[3];
    double d = M[4], e = M[5], f = M[6], t1 = M[7];
    double g = M[8], h = M[9], ii = M[10], t2 = M[11];
    double A00 = e*ii - f*h, A01 = c*h - b*ii, A02 = b*f - c*e;
    double A10 = f*g - d*ii, A11 = a*ii - c*g, A12 = c*d - a*f;
    double A20 = d*h - e*g,  A21 = b*g - a*h,  A22 = a*e - b*d;
    double det = a*A00 + b*A10 + c*A20;
    double inv = 1.0 / det;
    double r00 = A00*inv, r01 = A01*inv, r02 = A02*inv;
    double r10 = A10*inv, r11 = A11*inv, r12 = A12*inv;
    double r20 = A20*inv, r21 = A21*inv, r22 = A22*inv;
    o[0] = (float)r00; o[1] = (float)r01; o[2]  = (float)r02;
    o[3] = (float)(-(r00*t0 + r01*t1 + r02*t2));
    o[4] = (float)r10; o[5] = (float)r11; o[6]  = (float)r12;
    o[7] = (float)(-(r10*t0 + r11*t1 + r12*t2));
    o[8] = (float)r20; o[9] = (float)r21; o[10] = (float)r22;
    o[11] = (float)(-(r20*t0 + r21*t1 + r22*t2));
}

// ---------------------------------------------------------------------------
// Kernel 1: prep (verbatim R5). W (123x256) -> wt2 k-pair-interleaved +
// transposed (o zero-padded to 128): wt2[(k/2)*256 + o*2 + (k&1)].
// Block 0 also inverts the 24 cam2ego matrices.
// ---------------------------------------------------------------------------
__global__ __launch_bounds__(256) void k_pre(
    const float* __restrict__ wd, const float* __restrict__ c2e,
    float* __restrict__ wt2, float* __restrict__ e2c) {
    const int o = blockIdx.x;   // 0..127
    const int k = threadIdx.x;  // 0..255
    float v = (o < NOUT) ? wd[(size_t)o * CI + k] : 0.f;
    wt2[(size_t)(k >> 1) * 256 + o * 2 + (k & 1)] = v;
    if (blockIdx.x == 0 && k < NB * NC)
        inv_rigid(c2e + k * 16, e2c + k * 12);
}

// ---------------------------------------------------------------------------
// Kernel 2: depth/feat head. Grid 264 x 2: blockIdx.y selects the o-half
// (0: outputs 0..63 = logits+feat c0..4; 1: outputs 64..127 = feat c5..63).
// 512-thread blocks (8 waves), wave wv owns the 8-output strip
// o0 = 64*by + 8*wv (wave-uniform -> one s_load_dwordx16 of W per k-pair).
// Lane = px reads A as conflict-free ds_read_b64 from the k-pair-interleaved
// LDS tile; 8 v_pk_fma_f32 per k2. 528 blocks (~2/CU) x 8 waves = 4+
// waves/SIMD; __launch_bounds__(512,4) caps VGPR at 128 (kernel needs ~70,
// NO spill — R8's (1024,8)=64-VGPR cap likely spilled). Per-output k-order
// identical to R5 -> identical numerics.
// ---------------------------------------------------------------------------
__global__ __launch_bounds__(512, 4) void k_head(
    const float* __restrict__ img, const float* __restrict__ wt2,
    const float* __restrict__ bd, float* __restrict__ depth_out,
    float* __restrict__ feat_ws) {
    __shared__ float smem[64 * 69 + 64];  // staging 32x130 overlaid, X[64][69] after
    float* S = smem + 64 * 69;

    const int tid = threadIdx.x;         // 0..511
    const int wv  = tid >> 6;            // 0..7
    const int ln  = tid & 63;            // px
    const int p0  = blockIdx.x * 64;     // 64 | 704 -> tile never crosses (b,n)
    const int bn  = p0 / HW;
    const int hw0 = p0 - bn * HW;
    const int ob  = blockIdx.y << 6;     // 0 or 64
    const int o0  = __builtin_amdgcn_readfirstlane(ob + (wv << 3));

    const float* imgb = img + (size_t)bn * CI * HW + hw0;

    v2f acc[8];                           // {even-k, odd-k} partial sums
#pragma unroll
    for (int j = 0; j < 8; ++j) acc[j] = (v2f)(0.f);

    for (int kc = 0; kc < 4; ++kc) {
        // stage A chunk: 64 k x 64 px, k-pair interleaved, row stride 130.
        // Per instr: one kl row x 64 px -> 256B coalesced global read,
        // 2-way (free) LDS write conflict.
#pragma unroll
        for (int it = 0; it < 8; ++it) {
            int i = tid + it * 512;
            int kl = i >> 6, px = i & 63;
            smem[(kl >> 1) * 130 + px * 2 + (kl & 1)] =
                imgb[(size_t)(kc * 64 + kl) * HW + px];
        }
        __syncthreads();
#pragma unroll 4
        for (int k2 = 0; k2 < 32; ++k2) {
            v2f a = *(const v2f*)(smem + k2 * 130 + ln * 2);  // conflict-free b64
            const v2f* w =
                (const v2f*)(wt2 + (size_t)(kc * 32 + k2) * 256) + o0;  // s_load x16
#pragma unroll
            for (int j = 0; j < 8; ++j)
                acc[j] = __builtin_elementwise_fma(a, w[j], acc[j]);
        }
        __syncthreads();
    }

    // epilogue into X[64][69] (odd stride -> conflict-free column writes):
    // col = o - ob, rows = px
    float* X = smem;
#pragma unroll
    for (int j = 0; j < 8; ++j) {
        int o = o0 + j;
        if (o < NOUT)
            X[ln * 69 + (o - ob)] = (acc[j].x + acc[j].y) + bd[o];
    }
    __syncthreads();

    if (ob == 0) {
        // feat c = 0..4 from cols 59..63 (320 elems)
        if (tid < 320) {
            int p = tid / 5, c = tid - p * 5;
            feat_ws[(size_t)(p0 + p) * CO + c] = X[p * 69 + 59 + c];
        }
        // softmax over cols 0..58, one thread per pixel (same math as R5)
        if (tid < 64) {
            float* row = X + tid * 69;
            float m = row[0];
            for (int o = 1; o < D_BINS; ++o) m = fmaxf(m, row[o]);
            float s = 0.f;
            for (int o = 0; o < D_BINS; ++o) {
                float e = __expf(row[o] - m);
                row[o] = e;
                s += e;
            }
            S[tid] = 1.f / s;
        }
        __syncthreads();
        // depth: contiguous [p0*59, (p0+64)*59) -> coalesced
        for (int g = tid; g < 64 * D_BINS; g += 512) {
            int p = g / D_BINS;
            int o = g - p * D_BINS;
            depth_out[(size_t)p0 * D_BINS + g] = X[p * 69 + o] * S[p];
        }
    } else {
        // feat c = 5..63 from cols 0..58 (o = 64..122; o >= 123 dropped)
        for (int g = tid; g < 64 * D_BINS; g += 512) {
            int p = g / D_BINS;
            int j = g - p * D_BINS;
            feat_ws[(size_t)(p0 + p) * CO + 5 + j] = X[p * 69 + j];
        }
    }
}

// ---------------------------------------------------------------------------
// Kernel 3: project voxels, gather depth weight + feat, splat to BEV.
// Verbatim R5 (best measured): 1024 blocks (4/CU), reads precomputed e2c.
// Per camera n: projection phase computes each (x,z) sample's {hw, weight}
// once into LDS; accumulate phase broadcasts to the 4 channel-quarter
// threads (feat gathers + FMAs only).
// ---------------------------------------------------------------------------
__global__ __launch_bounds__(256) void k_splat(
    const float* __restrict__ e2c, const float* __restrict__ Kmat,
    const float* __restrict__ depth_g, const float* __restrict__ feat_ws,
    float* __restrict__ bev) {
    __shared__ int   hw_s[ZD][64];
    __shared__ float wgt_s[ZD][64];

    const int tx = threadIdx.x;          // 0..63 -> x
    const int cq = threadIdx.y;          // 0..3  -> channel quarter / z-slice
    const int x = blockIdx.x * 64 + tx;
    const int y = blockIdx.y;
    const int b = blockIdx.z;
    const float wx = (float)x * 0.8f + (-51.2f);
    const float wy = (float)y * 0.8f + (-51.2f);

    float acc[16];
#pragma unroll
    for (int m = 0; m < 16; ++m) acc[m] = 0.f;

    for (int n = 0; n < NC; ++n) {
        const int bn = b * NC + n;
        const float* E = e2c + bn * 12;
        const float* Km = Kmat + bn * 9;
        const float k00 = Km[0], k01 = Km[1], k02 = Km[2];
        const float k10 = Km[3], k11 = Km[4], k12 = Km[5];
        const float e02 = E[2], e12 = E[6], e22 = E[10];
        const float bx0 = E[0] * wx + E[1] * wy + E[3];
        const float bx1 = E[4] * wx + E[5] * wy + E[7];
        const float bx2 = E[8] * wx + E[9] * wy + E[11];

        // ---- projection phase: thread (tx,cq) owns z = cq and cq+4 ----
#pragma unroll
        for (int zz = 0; zz < 2; ++zz) {
            const int z = cq + zz * 4;
            if (z < ZD) {
                const float wz = -2.5f + (float)z;
                const float cx = bx0 + e02 * wz;
                const float cy = bx1 + e12 * wz;
                const float cz = bx2 + e22 * wz;
                const float zs = fmaxf(cz, 0.1f);
                const float rz = 1.0f / zs;         // IEEE divide
                const float xn = cx * rz;
                const float yn = cy * rz;
                const float fu = (k00 * xn + k01 * yn + k02) * 0.0625f;
                const float fv = (k10 * xn + k11 * yn + k12) * 0.0625f;
                const int bin = (int)(cz - 1.0f);   // trunc, matches astype(int32)
                const bool valid = (fu >= 0.f) & (fu < (float)W_IMG) &
                                   (fv >= 0.f) & (fv < (float)H_IMG) &
                                   (cz > 0.5f) & (bin >= 0) & (bin < D_BINS);
                int hw = -1;
                float wgt = 0.f;
                if (valid) {
                    int u = (int)fu;                // valid => in range
                    int v = (int)fv;
                    hw = v * W_IMG + u;
                    wgt = depth_g[((size_t)bn * HW + hw) * D_BINS + bin];
                }
                hw_s[z][tx] = hw;
                wgt_s[z][tx] = wgt;
            }
        }
        __syncthreads();

        // ---- accumulate phase: z ascending ----
#pragma unroll
        for (int z = 0; z < ZD; ++z) {
            const int hw = hw_s[z][tx];       // same addr across cq: broadcast
            if (hw >= 0) {
                const float wgt = wgt_s[z][tx];
                const float4* fp =
                    (const float4*)(feat_ws + ((size_t)bn * HW + hw) * CO + cq * 16);
                float4 f0 = fp[0], f1 = fp[1], f2 = fp[2], f3 = fp[3];
                acc[0]  = fmaf(wgt, f0.x, acc[0]);
                acc[1]  = fmaf(wgt, f0.y, acc[1]);
                acc[2]  = fmaf(wgt, f0.z, acc[2]);
                acc[3]  = fmaf(wgt, f0.w, acc[3]);
                acc[4]  = fmaf(wgt, f1.x, acc[4]);
                acc[5]  = fmaf(wgt, f1.y, acc[5]);
                acc[6]  = fmaf(wgt, f1.z, acc[6]);
                acc[7]  = fmaf(wgt, f1.w, acc[7]);
                acc[8]  = fmaf(wgt, f2.x, acc[8]);
                acc[9]  = fmaf(wgt, f2.y, acc[9]);
                acc[10] = fmaf(wgt, f2.z, acc[10]);
                acc[11] = fmaf(wgt, f2.w, acc[11]);
                acc[12] = fmaf(wgt, f3.x, acc[12]);
                acc[13] = fmaf(wgt, f3.y, acc[13]);
                acc[14] = fmaf(wgt, f3.z, acc[14]);
                acc[15] = fmaf(wgt, f3.w, acc[15]);
            }
        }
        __syncthreads();   // LDS reused next n
    }
    // out[b][c][y][x], c = cq*16 + m; 64 lanes = consecutive x -> coalesced
    float* ob = bev + (((size_t)b * CO + cq * 16) * YD + y) * XD + x;
#pragma unroll
    for (int m = 0; m < 16; ++m) ob[(size_t)m * YD * XD] = acc[m];
}

extern "C" void kernel_launch(void* const* d_in, const int* in_sizes, int n_in,
                              void* d_out, int out_size, void* d_ws, size_t ws_size,
                              hipStream_t stream) {
    const float* img  = (const float*)d_in[0];  // (B,N,256,16,44)
    const float* c2e  = (const float*)d_in[1];  // (B,N,4,4)
    const float* Kmat = (const float*)d_in[2];  // (B,N,3,3)
    const float* wd   = (const float*)d_in[3];  // (123,256)
    const float* bd   = (const float*)d_in[4];  // (123,)
    float* bev = (float*)d_out;                         // (B,64,128,128)
    float* depth_out = bev + (size_t)NB * CO * YD * XD; // (B,N,16,44,59)
    float* feat_ws = (float*)d_ws;                      // NPIX*64 floats
    float* wt2 = feat_ws + (size_t)NPIX * CO;           // 128*256 floats
    float* e2c = wt2 + 128 * 256;                       // 24*12 floats

    k_pre<<<128, 256, 0, stream>>>(wd, c2e, wt2, e2c);
    k_head<<<dim3(NPIX / 64, 2), 512, 0, stream>>>(img, wt2, bd, depth_out, feat_ws);
    k_splat<<<dim3(2, YD, NB), dim3(64, 4, 1), 0, stream>>>(e2c, Kmat, depth_out,
                                                            feat_ws, bev);
}